// Round 2
// baseline (334.449 us; speedup 1.0000x reference)
//
#include <hip/hip_runtime.h>
#include <hip/hip_fp16.h>

#define CH 256
#define HH 96
#define WW 160
#define HW (HH * WW) // 15360

typedef _Float16 h4 __attribute__((ext_vector_type(4)));
typedef float f32x4 __attribute__((ext_vector_type(4)));

__device__ inline unsigned pk2f(float a, float b) {
    return (unsigned)__half_as_ushort(__float2half(a)) |
           ((unsigned)__half_as_ushort(__float2half(b)) << 16);
}

// v6: depth-2 raw-register prefetch. v4/v5 invariance (same 256 loads/wave,
// depth-1 slack, identical 153-155us despite occupancy/barrier/MFMA changes)
// says the kernel is vmem-latency bound: each commit's vmcnt wait has only
// ~one MFMA section of slack. Fix: TWO named raw-register sets (A/B, rule
// #20: no runtime indexing -> no scratch) + 2x-unrolled main loop, so loads
// for chunk c are issued 2 iterations before their commit -> 32 loads in
// flight per wave, vmcnt(16) counted waits. Cost: +28 VGPR (~164 total incl
// 72 AGPR, still 3 waves/SIMD; launch_bounds(256,3)).
__global__ __launch_bounds__(256, 3)
void corr_v6(const float* __restrict__ Fp, const float* __restrict__ Sp,
             float* __restrict__ out) {
    // [buf2][row12][jt2][qq4][n16] : uint2 = 4 halves = 4 channels of group qq
    __shared__ uint2 sS[2 * 12 * 128]; // 24576 B

    const int bid = blockIdx.x;
    const int b   = bid & 7;       // batch-per-XCD swizzle
    const int rem = bid >> 3;      // 0..239
    const int y0  = (rem / 10) * 4;
    const int x0  = (rem % 10) * 16;

    const int t    = threadIdx.x;
    const int lane = t & 63;
    const int wv   = t >> 6;
    const int q    = lane >> 4;
    const int n    = lane & 15;

    const float*  Fb  = Fp + (size_t)b * CH * HW;
    const float2* Sb2 = (const float2*)(Sp + (size_t)b * CH * HW);

    // ---- staging lane map: (np, qq, jt)
    const int np = lane & 7;
    const int qq = (lane >> 3) & 3;
    const int jt = (lane >> 5) & 1;
    const int gx = x0 - 4 + jt * 16 + np * 2;
    const bool xok = (gx >= 0) & (gx + 1 < WW);

    bool okv[3];
    int  sOff[3]; // float2-offsets from Sb2
#pragma unroll
    for (int i = 0; i < 3; i++) {
        const int row = i * 4 + wv;
        const int gy  = y0 - 4 + row;
        okv[i] = ((unsigned)gy < HH) & xok;
        sOff[i] = okv[i] ? (qq * 4) * (HW / 2) + gy * (WW / 2) + (gx >> 1) : 0;
    }
    int fOff = (q * 4) * HW + (y0 + wv) * WW + x0 + n;

    // ---- two raw prefetch register sets (28 VGPR each)
    float2 rawSA[3][4];
    float  rawFA[4];
    float2 rawSB[3][4];
    float  rawFB[4];
    h4     av;

    auto load_set = [&](float2 (&rS)[3][4], float (&rF)[4]) {
#pragma unroll
        for (int i = 0; i < 3; i++)
#pragma unroll
            for (int j = 0; j < 4; j++)
                rS[i][j] = Sb2[sOff[i] + j * (HW / 2)];
#pragma unroll
        for (int j = 0; j < 4; j++)
            rF[j] = Fb[fOff + j * HW];
#pragma unroll
        for (int i = 0; i < 3; i++) sOff[i] += 8 * HW;  // +16 planes (float2 units)
        fOff += 16 * HW;
    };

    const int wrow = jt * 64 + qq * 16 + np * 2;

    auto commit_set = [&](float2 (&rS)[3][4], float (&rF)[4], int wb) {
        h4 a;
#pragma unroll
        for (int j = 0; j < 4; j++) a[j] = (_Float16)rF[j];
        av = a;
#pragma unroll
        for (int i = 0; i < 3; i++) {
            float ax[4], ay[4];
#pragma unroll
            for (int j = 0; j < 4; j++) {
                ax[j] = okv[i] ? rS[i][j].x : 0.0f;
                ay[j] = okv[i] ? rS[i][j].y : 0.0f;
            }
            uint4 v;
            v.x = pk2f(ax[0], ax[1]);  // col gx   : channels 0..3 of group qq
            v.y = pk2f(ax[2], ax[3]);
            v.z = pk2f(ay[0], ay[1]);  // col gx+1
            v.w = pk2f(ay[2], ay[3]);
            *(uint4*)&sS[wb + (i * 4 + wv) * 128 + wrow] = v;
        }
    };

    f32x4 acc[9][2];
#pragma unroll
    for (int dy = 0; dy < 9; dy++) {
        f32x4 z = {0.f, 0.f, 0.f, 0.f};
        acc[dy][0] = z;
        acc[dy][1] = z;
    }

    // ---- prologue: A=chunk0, B=chunk1 issued; commit chunk0; A=chunk2 issued
    load_set(rawSA, rawFA);      // chunk 0
    load_set(rawSB, rawFB);      // chunk 1
    commit_set(rawSA, rawFA, 0); // chunk 0 -> buf0 (waits only A's 16 loads)
    load_set(rawSA, rawFA);      // chunk 2 in flight
    __syncthreads();

    // chunks: even -> set A, odd -> set B. buf = chunk&1.
#pragma unroll 1
    for (int ch = 0; ch < 16; ch += 2) {
        // ---- even chunk ch: MFMA from buf0
        {
            const uint2* rp = sS + wv * 128 + q * 16 + n;
#pragma unroll
            for (int dy = 0; dy < 9; dy++) {
                h4 b0 = *(const h4*)(rp + dy * 128);
                h4 b1 = *(const h4*)(rp + dy * 128 + 64);
                acc[dy][0] = __builtin_amdgcn_mfma_f32_16x16x16f16(av, b0, acc[dy][0], 0, 0, 0);
                acc[dy][1] = __builtin_amdgcn_mfma_f32_16x16x16f16(av, b1, acc[dy][1], 0, 0, 0);
            }
            commit_set(rawSB, rawFB, 1536);          // chunk ch+1 -> buf1 (vmcnt(16))
            if (ch < 13) load_set(rawSB, rawFB);     // chunk ch+3 in flight
            __syncthreads();
        }
        // ---- odd chunk ch+1: MFMA from buf1
        {
            const uint2* rp = sS + 1536 + wv * 128 + q * 16 + n;
#pragma unroll
            for (int dy = 0; dy < 9; dy++) {
                h4 b0 = *(const h4*)(rp + dy * 128);
                h4 b1 = *(const h4*)(rp + dy * 128 + 64);
                acc[dy][0] = __builtin_amdgcn_mfma_f32_16x16x16f16(av, b0, acc[dy][0], 0, 0, 0);
                acc[dy][1] = __builtin_amdgcn_mfma_f32_16x16x16f16(av, b1, acc[dy][1], 0, 0, 0);
            }
            if (ch < 14) {
                commit_set(rawSA, rawFA, 0);         // chunk ch+2 -> buf0 (vmcnt(16))
                if (ch < 12) load_set(rawSA, rawFA); // chunk ch+4 in flight
                __syncthreads();
            }
        }
    }

    // ---- epilogue: D row m=q*4+r, col n; dx+4 = jt*16 + n - m in [0,8].
    const int y = y0 + wv;
#pragma unroll
    for (int r = 0; r < 4; r++) {
        const int m = q * 4 + r;
#pragma unroll
        for (int jtt = 0; jtt < 2; jtt++) {
            const int dxp = jtt * 16 + n - m;
            if (dxp >= 0 && dxp <= 8) {
                float* p = out + ((size_t)(b * 81 + dxp) * HH + y) * WW + x0 + m;
#pragma unroll
                for (int dy = 0; dy < 9; dy++) {
                    p[(size_t)dy * 9 * HW] = acc[dy][jtt][r] * (1.0f / 256.0f);
                }
            }
        }
    }
}

extern "C" void kernel_launch(void* const* d_in, const int* in_sizes, int n_in,
                              void* d_out, int out_size, void* d_ws, size_t ws_size,
                              hipStream_t stream) {
    const float* F = (const float*)d_in[0];
    const float* S = (const float*)d_in[1];
    float* o = (float*)d_out;
    corr_v6<<<dim3(1920), dim3(256), 0, stream>>>(F, S, o);
}